// Round 19
// baseline (238.242 us; speedup 1.0000x reference)
//
#include <hip/hip_runtime.h>
#include <hip/hip_bf16.h>
#include <stdint.h>

typedef float f32x4_t __attribute__((ext_vector_type(4)));
typedef float f32x16_t __attribute__((ext_vector_type(16)));
typedef short bf16x8_t __attribute__((ext_vector_type(8)));

#define MFMA32(a, b, c) __builtin_amdgcn_mfma_f32_32x32x16_bf16((a), (b), (c), 0, 0, 0)
#define MFMA16(a, b, c) __builtin_amdgcn_mfma_f32_16x16x32_bf16((a), (b), (c), 0, 0, 0)

static __device__ __forceinline__ unsigned short f2bf(float f) {
  union { float f; unsigned int u; } v;
  v.f = f;
  unsigned int u = v.u;
  unsigned int r = (u + 0x7fffu + ((u >> 16) & 1u)) >> 16;  // RNE
  return (unsigned short)r;
}

static __device__ __forceinline__ void gll16(const unsigned short* g, unsigned short* l) {
  __builtin_amdgcn_global_load_lds(
      (const __attribute__((address_space(1))) unsigned int*)g,
      (__attribute__((address_space(3))) unsigned int*)l, 16, 0, 0);
}

// -------- merged LayerNorm + weight-convert (one launch) --------
__global__ __launch_bounds__(256) void ln_cvt_kernel(
    const float* __restrict__ x, unsigned short* __restrict__ xn,
    const float* __restrict__ wq, const float* __restrict__ wk,
    const float* __restrict__ wv, const float* __restrict__ wo,
    unsigned short* __restrict__ wdst) {
  const int tid = threadIdx.x;
  if (blockIdx.x >= 16384) {
    const int idx = (blockIdx.x - 16384) * 256 + tid;  // < 1048576
    const int sel = idx >> 18;
    const int j = idx & 262143;
    const float* src = (sel == 0) ? wq : (sel == 1) ? wk : (sel == 2) ? wv : wo;
    float4 v = ((const float4*)src)[j];
    ushort4 o;
    o.x = f2bf(v.x); o.y = f2bf(v.y); o.z = f2bf(v.z); o.w = f2bf(v.w);
    ((ushort4*)(wdst + (size_t)sel * 1048576))[j] = o;
    return;
  }
  const int row = blockIdx.x;
  const int w = tid >> 6, lane = tid & 63;
  const float4 v = ((const float4*)(x + (size_t)row * 1024))[tid];
  float s = v.x + v.y + v.z + v.w;
  float s2 = v.x * v.x + v.y * v.y + v.z * v.z + v.w * v.w;
#pragma unroll
  for (int m = 32; m; m >>= 1) {
    s += __shfl_xor(s, m, 64);
    s2 += __shfl_xor(s2, m, 64);
  }
  __shared__ float red[2][4];
  if (lane == 0) { red[0][w] = s; red[1][w] = s2; }
  __syncthreads();
  const float S = red[0][0] + red[0][1] + red[0][2] + red[0][3];
  const float S2 = red[1][0] + red[1][1] + red[1][2] + red[1][3];
  const float mu = S * (1.0f / 1024.0f);
  const float var = S2 * (1.0f / 1024.0f) - mu * mu;
  const float rstd = rsqrtf(var + 1e-5f);
  ushort4 o;
  o.x = f2bf((v.x - mu) * rstd);
  o.y = f2bf((v.y - mu) * rstd);
  o.z = f2bf((v.z - mu) * rstd);
  o.w = f2bf((v.w - mu) * rstd);
  ((ushort4*)(xn + (size_t)row * 1024))[tid] = o;
}

// ====== 8-phase QKV GEMM, 32x32x16 MFMA (higher matrix-pipe rate) ============
// 256x256xBK64, 8 waves (2M x 4N), wave tile 128x64 = 4x2 C-tiles of 32x32
// (acc f32x16 each). Phase q = row-tile q: 4 k-steps x 2 col-tiles = 8 MFMA.
// A-frag: row = base + (lane&31), k-group = lane>>5 (chunk = ks*2 + l5).
// C/D: col = lane&31, row = (reg&3) + 8*(reg>>2) + 4*(lane>>5)  [m74/m101].
// Schedule identical to R13/R14: ph0/ph1 stage A(t+1), ph2/ph3 stage B(t+2),
// one barrier/phase, vmcnt(4) once per tile. Swizzle: chunk ^ (row&7) (=lane&7
// at read), both-sides; bank = f(chunk) only -> 2-way free.
__global__ __launch_bounds__(512, 1) void gemm_qkv8(
    const unsigned short* __restrict__ A, const unsigned short* __restrict__ B,
    unsigned short* __restrict__ Qo, unsigned short* __restrict__ Ko,
    unsigned short* __restrict__ Vo) {
  constexpr int K = 1024;
  constexpr int GX = 12;
  __shared__ __align__(16) unsigned short lds[65536];  // 128 KB
  const int tid = threadIdx.x;
  const int wv = tid >> 6, lane = tid & 63;
  const int l15 = lane & 15, l4 = lane >> 4;
  const int l31 = lane & 31, l5 = lane >> 5;
  const int wr = wv >> 2, wc = wv & 3;
  const int fid = blockIdx.y * GX + blockIdx.x;
  const int cpx = (GX * 64) >> 3;
  const int swz = (fid & 7) * cpx + (fid >> 3);
  const int bm = swz / GX, bn = swz % GX;

  const int srow = tid >> 3;
  const int schunk = ((tid & 7) ^ (srow & 7)) * 8;
  const unsigned short* Ag = A + (size_t)(bm * 256 + srow) * K + schunk;
  const unsigned short* Bg = B + (size_t)(bn * 256 + srow) * K + schunk;

  f32x16_t acc[4][2];
#pragma unroll
  for (int i = 0; i < 4; ++i)
#pragma unroll
    for (int j = 0; j < 2; ++j)
#pragma unroll
      for (int e = 0; e < 16; ++e) acc[i][j][e] = 0.f;
  bf16x8_t bfr[2][4];

#define STAGE_A(tt, hh, slot)                                                   \
  gll16(Ag + (size_t)((hh)*128) * K + (tt)*64,                                  \
        &lds[(slot)*16384 + (hh)*8192 + tid * 8]);                              \
  gll16(Ag + (size_t)((hh)*128 + 64) * K + (tt)*64,                             \
        &lds[(slot)*16384 + (hh)*8192 + 4096 + tid * 8]);
#define STAGE_B(tt, hh, slot)                                                   \
  gll16(Bg + (size_t)((hh)*128) * K + (tt)*64,                                  \
        &lds[32768 + (slot)*16384 + (hh)*8192 + tid * 8]);                      \
  gll16(Bg + (size_t)((hh)*128 + 64) * K + (tt)*64,                             \
        &lds[32768 + (slot)*16384 + (hh)*8192 + 4096 + tid * 8]);

#define VM4 asm volatile("s_waitcnt vmcnt(4)" ::: "memory")
#define VM0 asm volatile("s_waitcnt vmcnt(0)" ::: "memory")
#define ENDPH                                                                   \
  __builtin_amdgcn_s_barrier();                                                 \
  asm volatile("" ::: "memory");

#define PHASE(slot, q, BREAD, STAGE_CODE, VMCODE)                               \
  {                                                                             \
    const unsigned short* As_ = &lds[(slot)*16384 + wr * 8192];                 \
    bf16x8_t af[4];                                                             \
    _Pragma("unroll") for (int ks = 0; ks < 4; ++ks)                            \
        af[ks] = *(const bf16x8_t*)&As_[((q)*32 + l31) * 64 +                   \
                                        (((ks * 2 + l5) ^ (lane & 7)) * 8)];    \
    if (BREAD) {                                                                \
      const unsigned short* Bs_ = &lds[32768 + (slot)*16384 + (wc >> 1) * 8192];\
      _Pragma("unroll") for (int n2 = 0; n2 < 2; ++n2)                          \
      _Pragma("unroll") for (int ks = 0; ks < 4; ++ks)                          \
          bfr[n2][ks] = *(const bf16x8_t*)&Bs_[((wc & 1) * 64 + n2 * 32 + l31) *\
                                                   64 +                         \
                                               (((ks * 2 + l5) ^ (lane & 7)) * 8)];\
    }                                                                           \
    STAGE_CODE;                                                                 \
    __builtin_amdgcn_s_setprio(1);                                              \
    _Pragma("unroll") for (int ks = 0; ks < 4; ++ks)                            \
    _Pragma("unroll") for (int n2 = 0; n2 < 2; ++n2)                            \
        acc[q][n2] = MFMA32(af[ks], bfr[n2][ks], acc[q][n2]);                   \
    __builtin_amdgcn_s_setprio(0);                                              \
    VMCODE;                                                                     \
    ENDPH                                                                       \
  }

  STAGE_A(0, 0, 0);
  STAGE_A(0, 1, 0);
  STAGE_B(0, 0, 0);
  STAGE_B(0, 1, 0);
  STAGE_B(1, 0, 1);
  STAGE_B(1, 1, 1);
  VM4;
  __builtin_amdgcn_s_barrier();
  asm volatile("" ::: "memory");

#pragma unroll 1
  for (int t = 0; t < 14; t += 2) {
    PHASE(0, 0, 1, STAGE_A(t + 1, 0, 1), );
    PHASE(0, 1, 0, STAGE_A(t + 1, 1, 1), );
    PHASE(0, 2, 0, STAGE_B(t + 2, 0, 0), );
    PHASE(0, 3, 0, STAGE_B(t + 2, 1, 0), VM4);
    PHASE(1, 0, 1, STAGE_A(t + 2, 0, 0), );
    PHASE(1, 1, 0, STAGE_A(t + 2, 1, 0), );
    PHASE(1, 2, 0, STAGE_B(t + 3, 0, 1), );
    PHASE(1, 3, 0, STAGE_B(t + 3, 1, 1), VM4);
  }
  PHASE(0, 0, 1, STAGE_A(15, 0, 1), );
  PHASE(0, 1, 0, STAGE_A(15, 1, 1), );
  PHASE(0, 2, 0, , );
  PHASE(0, 3, 0, , VM0);
  PHASE(1, 0, 1, , );
  PHASE(1, 1, 0, , );
  PHASE(1, 2, 0, , );
  PHASE(1, 3, 0, , );

#undef PHASE
#undef STAGE_A
#undef STAGE_B
#undef VM4
#undef VM0
#undef ENDPH

  // -------- epilogue: LDS-bounce fragment stores (sw->global unchanged) ------
  asm volatile("s_waitcnt lgkmcnt(0)" ::: "memory");
  __builtin_amdgcn_s_barrier();
  unsigned short* sw = &lds[wv * 4608];  // 64 rows x 72 shorts, wave-private
  const int head = (bn & 3) * 4 + wc;
#pragma unroll
  for (int p = 0; p < 2; ++p) {
    const int sb64 = wr * 2 + p;
    if (bn < 8) {
      unsigned short* Fb = ((bn < 4) ? Qo : Ko) + ((size_t)(bm * 16 + head)) * 16384;
      // acc -> scratch using 32x32 C/D mapping
#pragma unroll
      for (int m2h = 0; m2h < 2; ++m2h)
#pragma unroll
        for (int n2 = 0; n2 < 2; ++n2)
#pragma unroll
          for (int reg = 0; reg < 16; ++reg)
            sw[(m2h * 32 + (reg & 3) + 8 * (reg >> 2) + 4 * l5) * 72 + n2 * 32 + l31] =
                f2bf(acc[2 * p + m2h][n2][reg]);
#pragma unroll
      for (int fg2 = 0; fg2 < 4; ++fg2)
#pragma unroll
        for (int hd = 0; hd < 2; ++hd) {
          const bf16x8_t v =
              *(const bf16x8_t*)&sw[(fg2 * 16 + l15) * 72 + hd * 32 + l4 * 8];
          *(bf16x8_t*)&Fb[(size_t)(((sb64 * 4 + fg2) * 2 + hd)) * 512 + lane * 8] = v;
        }
    } else {  // V: transposed scratch sw[d*72 + s_local]
#pragma unroll
      for (int m2h = 0; m2h < 2; ++m2h)
#pragma unroll
        for (int n2 = 0; n2 < 2; ++n2)
#pragma unroll
          for (int g = 0; g < 4; ++g) {
            ushort4 pk;
            pk.x = f2bf(acc[2 * p + m2h][n2][g * 4 + 0]);
            pk.y = f2bf(acc[2 * p + m2h][n2][g * 4 + 1]);
            pk.z = f2bf(acc[2 * p + m2h][n2][g * 4 + 2]);
            pk.w = f2bf(acc[2 * p + m2h][n2][g * 4 + 3]);
            *(ushort4*)&sw[(n2 * 32 + l31) * 72 + m2h * 32 + 8 * g + 4 * l5] = pk;
          }
      unsigned short* Vfb = Vo + ((size_t)(bm * 16 + head)) * 16384;
#pragma unroll
      for (int kb2 = 0; kb2 < 2; ++kb2)
#pragma unroll
        for (int n = 0; n < 4; ++n) {
          const bf16x8_t v =
              *(const bf16x8_t*)&sw[(n * 16 + l15) * 72 + kb2 * 32 + l4 * 8];
          *(bf16x8_t*)&Vfb[(size_t)((sb64 * 2 + kb2) * 4 + n) * 512 + lane * 8] = v;
        }
    }
  }
}

// ---------------- final GEMM: ring-of-3, BK=32, 32x32x16 MFMA ----------------
__global__ __launch_bounds__(512, 1) void gemm_fin(
    const unsigned short* __restrict__ A, const unsigned short* __restrict__ B,
    float* __restrict__ Cf, const float* __restrict__ bias,
    const float* __restrict__ resid, int GX) {
  constexpr int K = 1024;
  constexpr int NT = 32;
  __shared__ __align__(16) unsigned short lds[49152];
  const int tid = threadIdx.x;
  const int wv = tid >> 6, lane = tid & 63;
  const int l31 = lane & 31, l5 = lane >> 5;
  const int wr = wv >> 2, wc = wv & 3;
  const int fid = blockIdx.y * GX + blockIdx.x;
  const int cpx = (GX * gridDim.y) >> 3;
  const int swz = (fid & 7) * cpx + (fid >> 3);
  const int bm = swz / GX, bn = swz % GX;

  const int srow = wv * 16 + (lane >> 2);
  const int schunk = ((lane & 3) ^ ((lane >> 3) & 3)) * 8;
  const unsigned short* Ag = A + (size_t)(bm * 256 + srow) * K + schunk;
  const unsigned short* Bg = B + (size_t)(bn * 256 + srow) * K + schunk;

  f32x16_t acc[4][2];
#pragma unroll
  for (int i = 0; i < 4; ++i)
#pragma unroll
    for (int j = 0; j < 2; ++j)
#pragma unroll
      for (int e = 0; e < 16; ++e) acc[i][j][e] = 0.f;

#define STAGE(tt, slot)                                                         \
  {                                                                             \
    gll16(Ag + (tt)*32, &lds[(slot)*8192 + wv * 512]);                          \
    gll16(Ag + (size_t)128 * K + (tt)*32, &lds[(slot)*8192 + 4096 + wv * 512]); \
    gll16(Bg + (tt)*32, &lds[24576 + (slot)*8192 + wv * 512]);                  \
    gll16(Bg + (size_t)128 * K + (tt)*32,                                       \
          &lds[24576 + (slot)*8192 + 4096 + wv * 512]);                         \
  }

#define CONSUME(slot)                                                           \
  {                                                                             \
    const unsigned short* As_ = &lds[(slot)*8192];                              \
    const unsigned short* Bs_ = &lds[24576 + (slot)*8192];                      \
    bf16x8_t af[4][2], bf[2][2];                                                \
    _Pragma("unroll") for (int m2 = 0; m2 < 4; ++m2)                            \
    _Pragma("unroll") for (int ks = 0; ks < 2; ++ks)                            \
        af[m2][ks] = *(const bf16x8_t*)&As_[(wr * 128 + m2 * 32 + l31) * 32 +   \
                                            (((ks * 2 + l5) ^ ((lane >> 1) & 3)) * 8)];\
    _Pragma("unroll") for (int n2 = 0; n2 < 2; ++n2)                            \
    _Pragma("unroll") for (int ks = 0; ks < 2; ++ks)                            \
        bf[n2][ks] = *(const bf16x8_t*)&Bs_[(wc * 64 + n2 * 32 + l31) * 32 +    \
                                            (((ks * 2 + l5) ^ ((lane >> 1) & 3)) * 8)];\
    __builtin_amdgcn_s_setprio(1);                                              \
    _Pragma("unroll") for (int ks = 0; ks < 2; ++ks)                            \
    _Pragma("unroll") for (int m2 = 0; m2 < 4; ++m2)                            \
    _Pragma("unroll") for (int n2 = 0; n2 < 2; ++n2)                            \
        acc[m2][n2] = MFMA32(af[m2][ks], bf[n2][ks], acc[m2][n2]);              \
    __builtin_amdgcn_s_setprio(0);                                              \
  }

#define RING_SYNC(N)                                                            \
  asm volatile("s_waitcnt vmcnt(" #N ")" ::: "memory");                         \
  __builtin_amdgcn_s_barrier();                                                 \
  asm volatile("" ::: "memory");

  STAGE(0, 0);
  STAGE(1, 1);
  RING_SYNC(4);
#pragma unroll 1
  for (int t = 0; t < NT - 2; ++t) {
    STAGE(t + 2, (t + 2) % 3);
    CONSUME(t % 3);
    RING_SYNC(4);
  }
  CONSUME((NT - 2) % 3);
  RING_SYNC(0);
  CONSUME((NT - 1) % 3);

#undef STAGE
#undef CONSUME
#undef RING_SYNC

  const int rbase = bm * 256 + wr * 128;
  const int cbase = bn * 256 + wc * 64;
#pragma unroll
  for (int m2 = 0; m2 < 4; ++m2)
#pragma unroll
    for (int n2 = 0; n2 < 2; ++n2)
#pragma unroll
      for (int g = 0; g < 4; ++g) {
        const int row0 = rbase + m2 * 32 + 8 * g + 4 * l5;
        const int col = cbase + n2 * 32 + l31;
        const float bo = bias[col];
#pragma unroll
        for (int r = 0; r < 4; ++r) {
          const size_t idx = (size_t)(row0 + r) * 1024 + col;
          Cf[idx] = acc[m2][n2][g * 4 + r] + bo + resid[idx];
        }
      }
}

// ---------------- fused attention (R17/R18-proven, unchanged) -----------------
__global__ __launch_bounds__(256, 4) void attn_kernel(
    const unsigned short* __restrict__ Qf, const unsigned short* __restrict__ Kf,
    const unsigned short* __restrict__ Vf, unsigned short* __restrict__ O,
    const int* __restrict__ state, const float* __restrict__ etb,
    const float* __restrict__ srb, const float* __restrict__ rsb) {
  const int b = blockIdx.y;
  const int tid = threadIdx.x, w = tid >> 6, lane = tid & 63;
  const int l15 = lane & 15, l4 = lane >> 4;
  const int bx = blockIdx.x;       // 0..63
  const int qc = bx >> 2;          // q-chunk, shared by block
  const int h = (bx & 3) * 4 + w;  // head, distinct per wave
  const int qrow0 = qc * 16;

  __shared__ __align__(16) unsigned short Ps[4][16 * 136];  // 17.4 KB
  __shared__ __align__(16) unsigned short Bs[16 * 256];     // 8 KB bias tile
  __shared__ int state_s[256];                              // 1 KB

  state_s[tid] = (tid >= 3) ? state[b * 253 + tid - 3] : 0x7fffffff;
  const float e0 = etb[0], e1 = etb[1], e2 = etb[2], e3 = etb[3];
  const float sr0 = srb[0], sr1 = srb[1];
  const float rs0 = rsb[0], rs2 = rsb[2];
  __syncthreads();

  {
    const int kq0 = qrow0 + l4 * 4;
#pragma unroll
    for (int ff = 0; ff < 4; ++ff) {
      const int f = w * 4 + ff;
      const int k = f * 16 + l15;
      const bool kd = k >= 3;
      const int sk = state_s[k];
      ushort4 pk;
      unsigned short* e = (unsigned short*)&pk;
#pragma unroll
      for (int r = 0; r < 4; ++r) {
        const int q = kq0 + r;
        float bd = e0 + ((sk == state_s[q]) ? sr0 : sr1) + ((q < k) ? rs0 : rs2);
        float bv = (q >= 3) ? (kd ? bd : e1) : (kd ? e2 : e3);
        bv = (q == k) ? 0.f : bv;
        e[r] = f2bf(bv);
      }
      *(ushort4*)&Bs[f * 256 + lane * 4] = pk;
    }
  }
  __syncthreads();

  const unsigned short* Qb_ = Qf + ((size_t)(b * 16 + h)) * 16384 + lane * 8;
  const bf16x8_t qf0 = *(const bf16x8_t*)(Qb_ + (size_t)qc * 1024);
  const bf16x8_t qf1 = *(const bf16x8_t*)(Qb_ + (size_t)qc * 1024 + 512);

  const unsigned short* Kb_ = Kf + ((size_t)(b * 16 + h)) * 16384 + lane * 8;
  const unsigned short* Vb_ = Vf + ((size_t)(b * 16 + h)) * 16384 + lane * 8;

  const int qr0 = qrow0 + l4 * 4;
  f32x4_t oacc[4];
#pragma unroll
  for (int n = 0; n < 4; ++n) oacc[n] = (f32x4_t){0.f, 0.f, 0.f, 0.f};
  float rsum[4] = {0.f, 0.f, 0.f, 0.f};

#pragma unroll
  for (int half = 0; half < 2; ++half) {
    f32x4_t sc[8];
#pragma unroll
    for (int f = 0; f < 8; ++f) sc[f] = (f32x4_t){0.f, 0.f, 0.f, 0.f};
#pragma unroll
    for (int qtr = 0; qtr < 2; ++qtr) {
      bf16x8_t kr[8];
#pragma unroll
      for (int i = 0; i < 8; ++i)
        kr[i] = *(const bf16x8_t*)(Kb_ + (size_t)(half * 16 + qtr * 8 + i) * 512);
#pragma unroll
      for (int f = 0; f < 4; ++f) {
        sc[qtr * 4 + f] = MFMA16(qf0, kr[2 * f], sc[qtr * 4 + f]);
        sc[qtr * 4 + f] = MFMA16(qf1, kr[2 * f + 1], sc[qtr * 4 + f]);
      }
    }

    bf16x8_t vr0[8];
#pragma unroll
    for (int i = 0; i < 8; ++i)
      vr0[i] = *(const bf16x8_t*)(Vb_ + (size_t)(half * 16 + i) * 512);

#pragma unroll
    for (int f = 0; f < 8; ++f) {
      const ushort4 bt = *(const ushort4*)&Bs[(half * 8 + f) * 256 + lane * 4];
      const unsigned short* bte = (const unsigned short*)&bt;
#pragma unroll
      for (int r = 0; r < 4; ++r) {
        union { unsigned int u; float fl; } cv;
        cv.u = (unsigned int)bte[r] << 16;
        const float p = __expf(fmaf(sc[f][r], 0.125f, cv.fl));
        rsum[r] += p;
        Ps[w][(l4 * 4 + r) * 136 + f * 16 + l15] = f2bf(p);
      }
    }

#pragma unroll
    for (int kbl = 0; kbl < 2; ++kbl) {
      const bf16x8_t pf = *(const bf16x8_t*)&Ps[w][l15 * 136 + kbl * 32 + l4 * 8];
#pragma unroll
      for (int n = 0; n < 4; ++n) oacc[n] = MFMA16(pf, vr0[kbl * 4 + n], oacc[n]);
    }
    bf16x8_t vr1[8];
#pragma unroll
    for (int i = 0; i < 8; ++i)
      vr1[i] = *(const bf16x8_t*)(Vb_ + (size_t)(half * 16 + 8 + i) * 512);
#pragma unroll
    for (int kbl = 0; kbl < 2; ++kbl) {
      const bf16x8_t pf =
          *(const bf16x8_t*)&Ps[w][l15 * 136 + (2 + kbl) * 32 + l4 * 8];
#pragma unroll
      for (int n = 0; n < 4; ++n) oacc[n] = MFMA16(pf, vr1[kbl * 4 + n], oacc[n]);
    }
  }

#pragma unroll
  for (int m = 1; m < 16; m <<= 1)
#pragma unroll
    for (int r = 0; r < 4; ++r) rsum[r] += __shfl_xor(rsum[r], m, 64);
  float rinv[4];
#pragma unroll
  for (int r = 0; r < 4; ++r) rinv[r] = 1.0f / rsum[r];
  unsigned short* Op = O + (size_t)(b * 256 + qr0) * 1024 + h * 64;
#pragma unroll
  for (int n = 0; n < 4; ++n)
#pragma unroll
    for (int r = 0; r < 4; ++r)
      Op[(size_t)r * 1024 + n * 16 + l15] = f2bf(oacc[n][r] * rinv[r]);
}

extern "C" void kernel_launch(void* const* d_in, const int* in_sizes, int n_in,
                              void* d_out, int out_size, void* d_ws, size_t ws_size,
                              hipStream_t stream) {
  const float* x = (const float*)d_in[0];
  const int* state = (const int*)d_in[1];
  const float* WQ = (const float*)d_in[3];
  const float* WK = (const float*)d_in[4];
  const float* WV = (const float*)d_in[5];
  const float* WO = (const float*)d_in[6];
  const float* bO = (const float*)d_in[7];
  const float* etb = (const float*)d_in[8];
  const float* srb = (const float*)d_in[9];
  const float* rsb = (const float*)d_in[10];

  char* ws = (char*)d_ws;
  unsigned short* xn = (unsigned short*)(ws);                        // 32 MiB (reused as attn_out)
  unsigned short* Vf = (unsigned short*)(ws + (size_t)(32 << 20));   // 32 MiB (V fragments)
  unsigned short* WQKVb = (unsigned short*)(ws + (size_t)(64 << 20));// 6 MiB (WQ|WK|WV)
  unsigned short* WOb = WQKVb + (3 << 20);                           // 2 MiB
  unsigned short* Qf;
  unsigned short* Kf;
  if (ws_size >= ((size_t)136 << 20)) {
    Qf = (unsigned short*)(ws + (size_t)(72 << 20));   // 32 MiB
    Kf = (unsigned short*)(ws + (size_t)(104 << 20));  // 32 MiB
  } else {
    Qf = (unsigned short*)d_out;
    Kf = Qf + (16 << 20);
  }

  ln_cvt_kernel<<<20480, 256, 0, stream>>>(x, xn, WQ, WK, WV, WO, WQKVb);

  gemm_qkv8<<<dim3(12, 64), 512, 0, stream>>>(xn, WQKVb, Qf, Kf, Vf);

  attn_kernel<<<dim3(64, 64), 256, 0, stream>>>(Qf, Kf, Vf, xn, state, etb, srb, rsb);

  gemm_fin<<<dim3(4, 64), 512, 0, stream>>>(xn, WOb, (float*)d_out, bO, x, 4);
}

// Round 20
// 221.508 us; speedup vs baseline: 1.0755x; 1.0755x over previous
//
#include <hip/hip_runtime.h>
#include <hip/hip_bf16.h>
#include <stdint.h>

typedef float f32x4_t __attribute__((ext_vector_type(4)));
typedef short bf16x8_t __attribute__((ext_vector_type(8)));

#define MFMA16(a, b, c) __builtin_amdgcn_mfma_f32_16x16x32_bf16((a), (b), (c), 0, 0, 0)

static __device__ __forceinline__ unsigned short f2bf(float f) {
  union { float f; unsigned int u; } v;
  v.f = f;
  unsigned int u = v.u;
  unsigned int r = (u + 0x7fffu + ((u >> 16) & 1u)) >> 16;  // RNE
  return (unsigned short)r;
}

static __device__ __forceinline__ void gll16(const unsigned short* g, unsigned short* l) {
  __builtin_amdgcn_global_load_lds(
      (const __attribute__((address_space(1))) unsigned int*)g,
      (__attribute__((address_space(3))) unsigned int*)l, 16, 0, 0);
}

// -------- merged LayerNorm + weight-convert (one launch) --------
__global__ __launch_bounds__(256) void ln_cvt_kernel(
    const float* __restrict__ x, unsigned short* __restrict__ xn,
    const float* __restrict__ wq, const float* __restrict__ wk,
    const float* __restrict__ wv, const float* __restrict__ wo,
    unsigned short* __restrict__ wdst) {
  const int tid = threadIdx.x;
  if (blockIdx.x >= 16384) {
    const int idx = (blockIdx.x - 16384) * 256 + tid;  // < 1048576
    const int sel = idx >> 18;
    const int j = idx & 262143;
    const float* src = (sel == 0) ? wq : (sel == 1) ? wk : (sel == 2) ? wv : wo;
    float4 v = ((const float4*)src)[j];
    ushort4 o;
    o.x = f2bf(v.x); o.y = f2bf(v.y); o.z = f2bf(v.z); o.w = f2bf(v.w);
    ((ushort4*)(wdst + (size_t)sel * 1048576))[j] = o;
    return;
  }
  const int row = blockIdx.x;
  const int w = tid >> 6, lane = tid & 63;
  const float4 v = ((const float4*)(x + (size_t)row * 1024))[tid];
  float s = v.x + v.y + v.z + v.w;
  float s2 = v.x * v.x + v.y * v.y + v.z * v.z + v.w * v.w;
#pragma unroll
  for (int m = 32; m; m >>= 1) {
    s += __shfl_xor(s, m, 64);
    s2 += __shfl_xor(s2, m, 64);
  }
  __shared__ float red[2][4];
  if (lane == 0) { red[0][w] = s; red[1][w] = s2; }
  __syncthreads();
  const float S = red[0][0] + red[0][1] + red[0][2] + red[0][3];
  const float S2 = red[1][0] + red[1][1] + red[1][2] + red[1][3];
  const float mu = S * (1.0f / 1024.0f);
  const float var = S2 * (1.0f / 1024.0f) - mu * mu;
  const float rstd = rsqrtf(var + 1e-5f);
  ushort4 o;
  o.x = f2bf((v.x - mu) * rstd);
  o.y = f2bf((v.y - mu) * rstd);
  o.z = f2bf((v.z - mu) * rstd);
  o.w = f2bf((v.w - mu) * rstd);
  ((ushort4*)(xn + (size_t)row * 1024))[tid] = o;
}

// ================= 8-phase QKV GEMM (R13/R14-proven schedule) ================
// 256x256xBK64, 8 waves (2M x 4N), wave tile 128x64. LDS 128 KB, 2 slots each
// A/B. Tile t (slot t&1), 4 phases (C-quadrants, 16 MFMA; B-frags at ph0).
// ph0/ph1 stage A(t+1); ph2/ph3 stage B(t+2). One barrier/phase, vmcnt(4)
// once per tile. 16x16 MFMA: 2-way-free LDS reads (R19's 32x32 was 4-way
// conflicted, 655K->10M, regressed). Epilogue: Q/K/V in MFMA-fragment order.
__global__ __launch_bounds__(512, 1) void gemm_qkv8(
    const unsigned short* __restrict__ A, const unsigned short* __restrict__ B,
    unsigned short* __restrict__ Qo, unsigned short* __restrict__ Ko,
    unsigned short* __restrict__ Vo) {
  constexpr int K = 1024;
  constexpr int GX = 12;
  __shared__ __align__(16) unsigned short lds[65536];  // 128 KB
  const int tid = threadIdx.x;
  const int wv = tid >> 6, lane = tid & 63;
  const int l15 = lane & 15, l4 = lane >> 4;
  const int wr = wv >> 2, wc = wv & 3;
  const int fid = blockIdx.y * GX + blockIdx.x;
  const int cpx = (GX * 64) >> 3;
  const int swz = (fid & 7) * cpx + (fid >> 3);
  const int bm = swz / GX, bn = swz % GX;

  const int srow = tid >> 3;
  const int schunk = ((tid & 7) ^ (srow & 7)) * 8;
  const unsigned short* Ag = A + (size_t)(bm * 256 + srow) * K + schunk;
  const unsigned short* Bg = B + (size_t)(bn * 256 + srow) * K + schunk;

  f32x4_t acc[8][4];
#pragma unroll
  for (int i = 0; i < 8; ++i)
#pragma unroll
    for (int j = 0; j < 4; ++j) acc[i][j] = (f32x4_t){0.f, 0.f, 0.f, 0.f};
  bf16x8_t bfr[4][2];

#define STAGE_A(tt, hh, slot)                                                   \
  gll16(Ag + (size_t)((hh)*128) * K + (tt)*64,                                  \
        &lds[(slot)*16384 + (hh)*8192 + tid * 8]);                              \
  gll16(Ag + (size_t)((hh)*128 + 64) * K + (tt)*64,                             \
        &lds[(slot)*16384 + (hh)*8192 + 4096 + tid * 8]);
#define STAGE_B(tt, hh, slot)                                                   \
  gll16(Bg + (size_t)((hh)*128) * K + (tt)*64,                                  \
        &lds[32768 + (slot)*16384 + (hh)*8192 + tid * 8]);                      \
  gll16(Bg + (size_t)((hh)*128 + 64) * K + (tt)*64,                             \
        &lds[32768 + (slot)*16384 + (hh)*8192 + 4096 + tid * 8]);

#define VM4 asm volatile("s_waitcnt vmcnt(4)" ::: "memory")
#define VM0 asm volatile("s_waitcnt vmcnt(0)" ::: "memory")
#define ENDPH                                                                   \
  __builtin_amdgcn_s_barrier();                                                 \
  asm volatile("" ::: "memory");

#define PHASE(slot, q, BREAD, STAGE_CODE, VMCODE)                               \
  {                                                                             \
    const unsigned short* As_ = &lds[(slot)*16384 + wr * 8192];                 \
    bf16x8_t af[2][2];                                                          \
    _Pragma("unroll") for (int dm = 0; dm < 2; ++dm)                            \
    _Pragma("unroll") for (int kk = 0; kk < 2; ++kk)                            \
        af[dm][kk] = *(const bf16x8_t*)&As_[((2 * (q) + dm) * 16 + l15) * 64 +  \
                                            (((kk * 4 + l4) ^ (l15 & 7)) * 8)]; \
    if (BREAD) {                                                                \
      const unsigned short* Bs_ = &lds[32768 + (slot)*16384 + (wc >> 1) * 8192];\
      _Pragma("unroll") for (int n = 0; n < 4; ++n)                             \
      _Pragma("unroll") for (int kk = 0; kk < 2; ++kk)                          \
          bfr[n][kk] = *(const bf16x8_t*)&Bs_[((wc & 1) * 64 + n * 16 + l15) *  \
                                                  64 +                          \
                                              (((kk * 4 + l4) ^ (l15 & 7)) * 8)];\
    }                                                                           \
    STAGE_CODE;                                                                 \
    __builtin_amdgcn_s_setprio(1);                                              \
    _Pragma("unroll") for (int kk = 0; kk < 2; ++kk)                            \
    _Pragma("unroll") for (int dm = 0; dm < 2; ++dm)                            \
    _Pragma("unroll") for (int n = 0; n < 4; ++n)                               \
        acc[2 * (q) + dm][n] =                                                  \
            MFMA16(af[dm][kk], bfr[n][kk], acc[2 * (q) + dm][n]);               \
    __builtin_amdgcn_s_setprio(0);                                              \
    VMCODE;                                                                     \
    ENDPH                                                                       \
  }

  STAGE_A(0, 0, 0);
  STAGE_A(0, 1, 0);
  STAGE_B(0, 0, 0);
  STAGE_B(0, 1, 0);
  STAGE_B(1, 0, 1);
  STAGE_B(1, 1, 1);
  VM4;
  __builtin_amdgcn_s_barrier();
  asm volatile("" ::: "memory");

#pragma unroll 1
  for (int t = 0; t < 14; t += 2) {
    PHASE(0, 0, 1, STAGE_A(t + 1, 0, 1), );
    PHASE(0, 1, 0, STAGE_A(t + 1, 1, 1), );
    PHASE(0, 2, 0, STAGE_B(t + 2, 0, 0), );
    PHASE(0, 3, 0, STAGE_B(t + 2, 1, 0), VM4);
    PHASE(1, 0, 1, STAGE_A(t + 2, 0, 0), );
    PHASE(1, 1, 0, STAGE_A(t + 2, 1, 0), );
    PHASE(1, 2, 0, STAGE_B(t + 3, 0, 1), );
    PHASE(1, 3, 0, STAGE_B(t + 3, 1, 1), VM4);
  }
  PHASE(0, 0, 1, STAGE_A(15, 0, 1), );
  PHASE(0, 1, 0, STAGE_A(15, 1, 1), );
  PHASE(0, 2, 0, , );
  PHASE(0, 3, 0, , VM0);
  PHASE(1, 0, 1, , );
  PHASE(1, 1, 0, , );
  PHASE(1, 2, 0, , );
  PHASE(1, 3, 0, , );

#undef PHASE
#undef STAGE_A
#undef STAGE_B
#undef VM4
#undef VM0
#undef ENDPH

  // -------- epilogue: LDS-bounce fragment stores --------
  asm volatile("s_waitcnt lgkmcnt(0)" ::: "memory");
  __builtin_amdgcn_s_barrier();
  unsigned short* sw = &lds[wv * 4608];  // 64 rows x 72 shorts, wave-private
  const int head = (bn & 3) * 4 + wc;
#pragma unroll
  for (int p = 0; p < 2; ++p) {
    const int sb64 = wr * 2 + p;
    if (bn < 8) {
      unsigned short* Fb = ((bn < 4) ? Qo : Ko) + ((size_t)(bm * 16 + head)) * 16384;
#pragma unroll
      for (int i2 = 0; i2 < 4; ++i2)
#pragma unroll
        for (int j = 0; j < 4; ++j)
#pragma unroll
          for (int r = 0; r < 4; ++r)
            sw[(i2 * 16 + l4 * 4 + r) * 72 + j * 16 + l15] = f2bf(acc[p * 4 + i2][j][r]);
#pragma unroll
      for (int fg2 = 0; fg2 < 4; ++fg2)
#pragma unroll
        for (int hd = 0; hd < 2; ++hd) {
          const bf16x8_t v =
              *(const bf16x8_t*)&sw[(fg2 * 16 + l15) * 72 + hd * 32 + l4 * 8];
          *(bf16x8_t*)&Fb[(size_t)(((sb64 * 4 + fg2) * 2 + hd)) * 512 + lane * 8] = v;
        }
    } else {  // V: transposed scratch sw[d*72 + s_local]
#pragma unroll
      for (int i2 = 0; i2 < 4; ++i2)
#pragma unroll
        for (int j = 0; j < 4; ++j) {
          ushort4 pk;
          pk.x = f2bf(acc[p * 4 + i2][j][0]);
          pk.y = f2bf(acc[p * 4 + i2][j][1]);
          pk.z = f2bf(acc[p * 4 + i2][j][2]);
          pk.w = f2bf(acc[p * 4 + i2][j][3]);
          *(ushort4*)&sw[(j * 16 + l15) * 72 + i2 * 16 + l4 * 4] = pk;
        }
      unsigned short* Vfb = Vo + ((size_t)(bm * 16 + head)) * 16384;
#pragma unroll
      for (int kb2 = 0; kb2 < 2; ++kb2)
#pragma unroll
        for (int n = 0; n < 4; ++n) {
          const bf16x8_t v =
              *(const bf16x8_t*)&sw[(n * 16 + l15) * 72 + kb2 * 32 + l4 * 8];
          *(bf16x8_t*)&Vfb[(size_t)((sb64 * 2 + kb2) * 4 + n) * 512 + lane * 8] = v;
        }
    }
  }
}

// ---------------- final GEMM: ring-of-3, BK=32 (R13/R14-proven) --------------
__global__ __launch_bounds__(512, 1) void gemm_fin(
    const unsigned short* __restrict__ A, const unsigned short* __restrict__ B,
    float* __restrict__ Cf, const float* __restrict__ bias,
    const float* __restrict__ resid, int GX) {
  constexpr int K = 1024;
  constexpr int NT = 32;
  __shared__ __align__(16) unsigned short lds[49152];
  const int tid = threadIdx.x;
  const int wv = tid >> 6, lane = tid & 63;
  const int l15 = lane & 15, l4 = lane >> 4;
  const int wr = wv >> 2, wc = wv & 3;
  const int fid = blockIdx.y * GX + blockIdx.x;
  const int cpx = (GX * gridDim.y) >> 3;
  const int swz = (fid & 7) * cpx + (fid >> 3);
  const int bm = swz / GX, bn = swz % GX;

  const int srow = wv * 16 + (lane >> 2);
  const int schunk = ((lane & 3) ^ ((lane >> 3) & 3)) * 8;
  const unsigned short* Ag = A + (size_t)(bm * 256 + srow) * K + schunk;
  const unsigned short* Bg = B + (size_t)(bn * 256 + srow) * K + schunk;

  f32x4_t acc[8][4];
#pragma unroll
  for (int i = 0; i < 8; ++i)
#pragma unroll
    for (int j = 0; j < 4; ++j) acc[i][j] = (f32x4_t){0.f, 0.f, 0.f, 0.f};

#define STAGE(tt, slot)                                                         \
  {                                                                             \
    gll16(Ag + (tt)*32, &lds[(slot)*8192 + wv * 512]);                          \
    gll16(Ag + (size_t)128 * K + (tt)*32, &lds[(slot)*8192 + 4096 + wv * 512]); \
    gll16(Bg + (tt)*32, &lds[24576 + (slot)*8192 + wv * 512]);                  \
    gll16(Bg + (size_t)128 * K + (tt)*32,                                       \
          &lds[24576 + (slot)*8192 + 4096 + wv * 512]);                         \
  }

#define CONSUME(slot)                                                           \
  {                                                                             \
    const unsigned short* As_ = &lds[(slot)*8192];                              \
    const unsigned short* Bs_ = &lds[24576 + (slot)*8192];                      \
    const int cx = (l4 ^ ((l15 >> 1) & 3)) * 8;                                 \
    bf16x8_t af[8], bf[4];                                                      \
    _Pragma("unroll") for (int m = 0; m < 8; ++m)                               \
        af[m] = *(const bf16x8_t*)&As_[(wr * 128 + m * 16 + l15) * 32 + cx];    \
    _Pragma("unroll") for (int n = 0; n < 4; ++n)                               \
        bf[n] = *(const bf16x8_t*)&Bs_[(wc * 64 + n * 16 + l15) * 32 + cx];     \
    __builtin_amdgcn_s_setprio(1);                                              \
    _Pragma("unroll") for (int m = 0; m < 8; ++m)                               \
        _Pragma("unroll") for (int n = 0; n < 4; ++n)                           \
            acc[m][n] = MFMA16(af[m], bf[n], acc[m][n]);                        \
    __builtin_amdgcn_s_setprio(0);                                              \
  }

#define RING_SYNC(N)                                                            \
  asm volatile("s_waitcnt vmcnt(" #N ")" ::: "memory");                         \
  __builtin_amdgcn_s_barrier();                                                 \
  asm volatile("" ::: "memory");

  STAGE(0, 0);
  STAGE(1, 1);
  RING_SYNC(4);
#pragma unroll 1
  for (int t = 0; t < NT - 2; ++t) {
    STAGE(t + 2, (t + 2) % 3);
    CONSUME(t % 3);
    RING_SYNC(4);
  }
  CONSUME((NT - 2) % 3);
  RING_SYNC(0);
  CONSUME((NT - 1) % 3);

#undef STAGE
#undef CONSUME
#undef RING_SYNC

  const int rbase = bm * 256 + wr * 128;
  const int cbase = bn * 256 + wc * 64;
#pragma unroll
  for (int i = 0; i < 8; ++i) {
    const int row0 = rbase + i * 16 + l4 * 4;
#pragma unroll
    for (int j = 0; j < 4; ++j) {
      const int col = cbase + j * 16 + l15;
      const float bo = bias[col];
#pragma unroll
      for (int r = 0; r < 4; ++r) {
        const size_t idx = (size_t)(row0 + r) * 1024 + col;
        Cf[idx] = acc[i][j][r] + bo + resid[idx];
      }
    }
  }
}

// ---------------- fused attention: bias table + all-fragment inputs -----------
__global__ __launch_bounds__(256, 4) void attn_kernel(
    const unsigned short* __restrict__ Qf, const unsigned short* __restrict__ Kf,
    const unsigned short* __restrict__ Vf, unsigned short* __restrict__ O,
    const int* __restrict__ state, const float* __restrict__ etb,
    const float* __restrict__ srb, const float* __restrict__ rsb) {
  const int b = blockIdx.y;
  const int tid = threadIdx.x, w = tid >> 6, lane = tid & 63;
  const int l15 = lane & 15, l4 = lane >> 4;
  const int bx = blockIdx.x;       // 0..63
  const int qc = bx >> 2;          // q-chunk, shared by block
  const int h = (bx & 3) * 4 + w;  // head, distinct per wave
  const int qrow0 = qc * 16;

  __shared__ __align__(16) unsigned short Ps[4][16 * 136];  // 17.4 KB
  __shared__ __align__(16) unsigned short Bs[16 * 256];     // 8 KB bias tile
  __shared__ int state_s[256];                              // 1 KB

  state_s[tid] = (tid >= 3) ? state[b * 253 + tid - 3] : 0x7fffffff;
  const float e0 = etb[0], e1 = etb[1], e2 = etb[2], e3 = etb[3];
  const float sr0 = srb[0], sr1 = srb[1];
  const float rs0 = rsb[0], rs2 = rsb[2];
  __syncthreads();

  {
    const int kq0 = qrow0 + l4 * 4;
#pragma unroll
    for (int ff = 0; ff < 4; ++ff) {
      const int f = w * 4 + ff;
      const int k = f * 16 + l15;
      const bool kd = k >= 3;
      const int sk = state_s[k];
      ushort4 pk;
      unsigned short* e = (unsigned short*)&pk;
#pragma unroll
      for (int r = 0; r < 4; ++r) {
        const int q = kq0 + r;
        float bd = e0 + ((sk == state_s[q]) ? sr0 : sr1) + ((q < k) ? rs0 : rs2);
        float bv = (q >= 3) ? (kd ? bd : e1) : (kd ? e2 : e3);
        bv = (q == k) ? 0.f : bv;
        e[r] = f2bf(bv);
      }
      *(ushort4*)&Bs[f * 256 + lane * 4] = pk;
    }
  }
  __syncthreads();

  const unsigned short* Qb_ = Qf + ((size_t)(b * 16 + h)) * 16384 + lane * 8;
  const bf16x8_t qf0 = *(const bf16x8_t*)(Qb_ + (size_t)qc * 1024);
  const bf16x8_t qf1 = *(const bf16x8_t*)(Qb_ + (size_t)qc * 1024 + 512);

  const unsigned short* Kb_ = Kf + ((size_t)(b * 16 + h)) * 16384 + lane * 8;
  const unsigned short* Vb_ = Vf + ((size_t)(b * 16 + h)) * 16384 + lane * 8;

  const int qr0 = qrow0 + l4 * 4;
  f32x4_t oacc[4];
#pragma unroll
  for (int n = 0; n < 4; ++n) oacc[n] = (f32x4_t){0.f, 0.f, 0.f, 0.f};
  float rsum[4] = {0.f, 0.f, 0.f, 0.f};

#pragma unroll
  for (int half = 0; half < 2; ++half) {
    f32x4_t sc[8];
#pragma unroll
    for (int f = 0; f < 8; ++f) sc[f] = (f32x4_t){0.f, 0.f, 0.f, 0.f};
#pragma unroll
    for (int qtr = 0; qtr < 2; ++qtr) {
      bf16x8_t kr[8];
#pragma unroll
      for (int i = 0; i < 8; ++i)
        kr[i] = *(const bf16x8_t*)(Kb_ + (size_t)(half * 16 + qtr * 8 + i) * 512);
#pragma unroll
      for (int f = 0; f < 4; ++f) {
        sc[qtr * 4 + f] = MFMA16(qf0, kr[2 * f], sc[qtr * 4 + f]);
        sc[qtr * 4 + f] = MFMA16(qf1, kr[2 * f + 1], sc[qtr * 4 + f]);
      }
    }

    bf16x8_t vr0[8];
#pragma unroll
    for (int i = 0; i < 8; ++i)
      vr0[i] = *(const bf16x8_t*)(Vb_ + (size_t)(half * 16 + i) * 512);

#pragma unroll
    for (int f = 0; f < 8; ++f) {
      const ushort4 bt = *(const ushort4*)&Bs[(half * 8 + f) * 256 + lane * 4];
      const unsigned short* bte = (const unsigned short*)&bt;
#pragma unroll
      for (int r = 0; r < 4; ++r) {
        union { unsigned int u; float fl; } cv;
        cv.u = (unsigned int)bte[r] << 16;
        const float p = __expf(fmaf(sc[f][r], 0.125f, cv.fl));
        rsum[r] += p;
        Ps[w][(l4 * 4 + r) * 136 + f * 16 + l15] = f2bf(p);
      }
    }

#pragma unroll
    for (int kbl = 0; kbl < 2; ++kbl) {
      const bf16x8_t pf = *(const bf16x8_t*)&Ps[w][l15 * 136 + kbl * 32 + l4 * 8];
#pragma unroll
      for (int n = 0; n < 4; ++n) oacc[n] = MFMA16(pf, vr0[kbl * 4 + n], oacc[n]);
    }
    bf16x8_t vr1[8];
#pragma unroll
    for (int i = 0; i < 8; ++i)
      vr1[i] = *(const bf16x8_t*)(Vb_ + (size_t)(half * 16 + 8 + i) * 512);
#pragma unroll
    for (int kbl = 0; kbl < 2; ++kbl) {
      const bf16x8_t pf =
          *(const bf16x8_t*)&Ps[w][l15 * 136 + (2 + kbl) * 32 + l4 * 8];
#pragma unroll
      for (int n = 0; n < 4; ++n) oacc[n] = MFMA16(pf, vr1[kbl * 4 + n], oacc[n]);
    }
  }

#pragma unroll
  for (int m = 1; m < 16; m <<= 1)
#pragma unroll
    for (int r = 0; r < 4; ++r) rsum[r] += __shfl_xor(rsum[r], m, 64);
  float rinv[4];
#pragma unroll
  for (int r = 0; r < 4; ++r) rinv[r] = 1.0f / rsum[r];
  unsigned short* Op = O + (size_t)(b * 256 + qr0) * 1024 + h * 64;
#pragma unroll
  for (int n = 0; n < 4; ++n)
#pragma unroll
    for (int r = 0; r < 4; ++r)
      Op[(size_t)r * 1024 + n * 16 + l15] = f2bf(oacc[n][r] * rinv[r]);
}

extern "C" void kernel_launch(void* const* d_in, const int* in_sizes, int n_in,
                              void* d_out, int out_size, void* d_ws, size_t ws_size,
                              hipStream_t stream) {
  const float* x = (const float*)d_in[0];
  const int* state = (const int*)d_in[1];
  const float* WQ = (const float*)d_in[3];
  const float* WK = (const float*)d_in[4];
  const float* WV = (const float*)d_in[5];
  const float* WO = (const float*)d_in[6];
  const float* bO = (const float*)d_in[7];
  const float* etb = (const float*)d_in[8];
  const float* srb = (const float*)d_in[9];
  const float* rsb = (const float*)d_in[10];

  char* ws = (char*)d_ws;
  unsigned short* xn = (unsigned short*)(ws);                        // 32 MiB (reused as attn_out)
  unsigned short* Vf = (unsigned short*)(ws + (size_t)(32 << 20));   // 32 MiB (V fragments)
  unsigned short* WQKVb = (unsigned short*)(ws + (size_t)(64 << 20));// 6 MiB (WQ|WK|WV)
  unsigned short* WOb = WQKVb + (3 << 20);                           // 2 MiB
  unsigned short* Qf;
  unsigned short* Kf;
  if (ws_size >= ((size_t)136 << 20)) {
    Qf = (unsigned short*)(ws + (size_t)(72 << 20));   // 32 MiB
    Kf = (unsigned short*)(ws + (size_t)(104 << 20));  // 32 MiB
  } else {
    Qf = (unsigned short*)d_out;
    Kf = Qf + (16 << 20);
  }

  ln_cvt_kernel<<<20480, 256, 0, stream>>>(x, xn, WQ, WK, WV, WO, WQKVb);

  gemm_qkv8<<<dim3(12, 64), 512, 0, stream>>>(xn, WQKVb, Qf, Kf, Vf);

  attn_kernel<<<dim3(64, 64), 256, 0, stream>>>(Qf, Kf, Vf, xn, state, etb, srb, rsb);

  gemm_fin<<<dim3(4, 64), 512, 0, stream>>>(xn, WOb, (float*)d_out, bO, x, 4);
}